// Round 1
// baseline (107.425 us; speedup 1.0000x reference)
//
#include <hip/hip_runtime.h>
#include <hip/hip_bf16.h>

#define NEG 0.2f

typedef __attribute__((ext_vector_type(8))) short bf16x8;
typedef __attribute__((ext_vector_type(4))) float f32x4;
typedef __attribute__((ext_vector_type(4))) int int4v;

__device__ __forceinline__ float lrelu(float t){ return t > 0.f ? t : NEG * t; }

__device__ __forceinline__ unsigned short f2bf(float f){
  union { float f; unsigned int u; } v; v.f = f;
  unsigned int r = v.u + 0x7FFFu + ((v.u >> 16) & 1u);
  return (unsigned short)(r >> 16);
}

// ---------------- K1: h = x @ W  (f32, per 32-row tile) ----------------
__global__ __launch_bounds__(256) void k1_hgemm(const float* __restrict__ x,
                                                const float* __restrict__ W,
                                                float* __restrict__ h){
  __shared__ __align__(16) float Wl[128*128];
  __shared__ __align__(16) float xl[32*136];
  const int t = threadIdx.x;
  const long rowbase = (long)blockIdx.x * 32;
  {
    const f32x4* W4 = (const f32x4*)W;
    f32x4* Wl4 = (f32x4*)Wl;
#pragma unroll
    for (int i = 0; i < 16; ++i) Wl4[t + 256*i] = W4[t + 256*i];
    const int r = t >> 3, seg = t & 7;
    const f32x4* xs = (const f32x4*)(x + (rowbase + r)*128 + seg*16);
    f32x4* xd = (f32x4*)(xl + r*136 + seg*16);
#pragma unroll
    for (int i = 0; i < 4; ++i) xd[i] = xs[i];
  }
  __syncthreads();
  const int r = t >> 3, c = t & 7;
  f32x4 zro = {0.f, 0.f, 0.f, 0.f};
  f32x4 a0 = zro, a1 = zro, a2 = zro, a3 = zro;
  const float* xr = xl + r*136;
#pragma unroll 4
  for (int k = 0; k < 128; ++k){
    const float xv = xr[k];
    const f32x4* wk = (const f32x4*)(Wl + k*128 + c*16);
    a0 += xv * wk[0]; a1 += xv * wk[1]; a2 += xv * wk[2]; a3 += xv * wk[3];
  }
  f32x4* ho = (f32x4*)(h + (rowbase + r)*128 + c*16);
  ho[0] = a0; ho[1] = a1; ho[2] = a2; ho[3] = a3;
}

// ---------------- K_tr: ht[b][o][j] = bf16(h[b][j][o]) ----------------
__global__ __launch_bounds__(256) void k_tr(const float* __restrict__ h,
                                            unsigned short* __restrict__ ht){
  __shared__ __align__(16) unsigned short tl[64*80];
  const int t = threadIdx.x;
  const int bx = blockIdx.x;             // 8 * 32 * 2
  const int b  = bx >> 6;
  const int jt = (bx & 63) >> 1;
  const int ot = bx & 1;
  {
    const int jj = t >> 2, og = (t & 3) * 16;
    const f32x4* src = (const f32x4*)(h + ((long)(b*2048 + jt*64 + jj))*128 + ot*64 + og);
    unsigned int q[8];
#pragma unroll
    for (int i = 0; i < 4; ++i){
      f32x4 v = src[i];
      q[i*2]   = (unsigned int)f2bf(v[0]) | ((unsigned int)f2bf(v[1]) << 16);
      q[i*2+1] = (unsigned int)f2bf(v[2]) | ((unsigned int)f2bf(v[3]) << 16);
    }
    unsigned short* dstl = tl + jj*80 + og;
    *(int4v*)dstl       = *(int4v*)&q[0];
    *(int4v*)(dstl + 8) = *(int4v*)&q[4];
  }
  __syncthreads();
  const int ol = t >> 2, jg = (t & 3) * 16;
  unsigned int p[8];
#pragma unroll
  for (int i = 0; i < 8; ++i){
    unsigned int lo = tl[(jg + 2*i    )*80 + ol];
    unsigned int hi = tl[(jg + 2*i + 1)*80 + ol];
    p[i] = lo | (hi << 16);
  }
  unsigned short* dst = ht + (long)b*262144 + (long)(ot*64 + ol)*2048 + jt*64 + jg;
  ((int4v*)dst)[0] = *(int4v*)&p[0];
  ((int4v*)dst)[1] = *(int4v*)&p[4];
}

// ---------------- K2a: s_src, s_dst (one wave per row) ----------------
__global__ __launch_bounds__(256) void k2_s(const float* __restrict__ h,
                                            const float* __restrict__ a,
                                            float* __restrict__ ssrc,
                                            float* __restrict__ sdst){
  const int lane = threadIdx.x & 63;
  const long row = (long)blockIdx.x * 4 + (threadIdx.x >> 6);
  const float2 hv = ((const float2*)(h + row*128))[lane];
  const float2 as = ((const float2*)a)[lane];
  const float2 ad = ((const float2*)(a + 128))[lane];
  float ps = hv.x*as.x + hv.y*as.y;
  float pd = hv.x*ad.x + hv.y*ad.y;
#pragma unroll
  for (int off = 32; off >= 1; off >>= 1){
    ps += __shfl_down(ps, off);
    pd += __shfl_down(pd, off);
  }
  if (lane == 0){ ssrc[row] = ps; sdst[row] = pd; }
}

// ---------------- K2b: per-batch max of s_dst ----------------
__global__ __launch_bounds__(256) void k2_max(const float* __restrict__ sdst,
                                              float* __restrict__ M){
  __shared__ float red[256];
  const int b = blockIdx.x, t = threadIdx.x;
  float mx = -3.4e38f;
  for (int j = t; j < 2048; j += 256) mx = fmaxf(mx, sdst[b*2048 + j]);
  red[t] = mx; __syncthreads();
  for (int s = 128; s > 0; s >>= 1){
    if (t < s) red[t] = fmaxf(red[t], red[t+s]);
    __syncthreads();
  }
  if (t == 0) M[b] = red[0];
}

// ---------------- K2c: m_i = LR(s_i + M_b), rl_i = 1/sum_j exp(LR(s_i+s_j)-m_i) ----------------
__global__ __launch_bounds__(256) void k2_ml(const float* __restrict__ ssrc,
                                             const float* __restrict__ sdst,
                                             const float* __restrict__ M,
                                             float* __restrict__ marr,
                                             float* __restrict__ rlarr){
  const int lane = threadIdx.x & 63;
  const long row = (long)blockIdx.x * 4 + (threadIdx.x >> 6);
  const int b = (int)(row >> 11);
  const float si = ssrc[row];
  const float m = lrelu(si + M[b]);
  const float* sd = sdst + (long)b*2048;
  float sum = 0.f;
  for (int j = lane; j < 2048; j += 64)
    sum += __expf(lrelu(si + sd[j]) - m);
#pragma unroll
  for (int off = 32; off >= 1; off >>= 1) sum += __shfl_down(sum, off);
  if (lane == 0){ marr[row] = m; rlarr[row] = 1.f / sum; }
}

// ---------------- K3: out = LR( (adj + alpha) @ h ), fused MFMA GEMM ----------------
// grid: 8 batches * 32 row-tiles (BM=64); block: 256 = 4 waves, wave w owns rows w*16..w*16+15
__global__ __launch_bounds__(256) void k3_main(const float* __restrict__ adj,
                                               const unsigned short* __restrict__ ht,
                                               const float* __restrict__ ssrc,
                                               const float* __restrict__ sdst,
                                               const float* __restrict__ marr,
                                               const float* __restrict__ rlarr,
                                               float* __restrict__ out){
  __shared__ __align__(16) unsigned short htl[128*40];   // [o:128][j:32 (+8 pad)]
  const int t   = threadIdx.x;
  const int bx  = blockIdx.x;
  const int b   = bx >> 5;
  const int i0  = (bx & 31) * 64;
  const int wid = t >> 6, lane = t & 63;
  const int lr  = lane & 15, hi = lane >> 4;
  const int rowi = i0 + wid*16 + lr;
  const long rowg = (long)b*2048 + rowi;
  const float m_i  = marr[rowg];
  const float rl_i = rlarr[rowg];
  const float si   = ssrc[rowg];
  const float* adjrow = adj + ((long)b*2048 + rowi)*2048 + hi*8;
  const float* sdb    = sdst + (long)b*2048 + hi*8;
  const unsigned short* htg = ht + (long)b*262144;
  const int so = t >> 1, sjo = (t & 1) * 16;
  const unsigned short* hsrc = htg + (long)so*2048 + sjo;
  unsigned short* hdst = htl + so*40 + sjo;

  f32x4 zro = {0.f, 0.f, 0.f, 0.f};
  f32x4 acc[8];
#pragma unroll
  for (int i = 0; i < 8; ++i) acc[i] = zro;

  // prefetch step 0
  int4v hc0 = *(const int4v*)(hsrc);
  int4v hc1 = *(const int4v*)(hsrc + 8);
  f32x4 av0 = *(const f32x4*)(adjrow);
  f32x4 av1 = *(const f32x4*)(adjrow + 4);
  f32x4 sd0 = *(const f32x4*)(sdb);
  f32x4 sd1 = *(const f32x4*)(sdb + 4);

  for (int kt = 0; kt < 64; ++kt){
    const int jn = (kt < 63 ? kt + 1 : kt) * 32;   // next step (clamped)
    int4v hn0 = *(const int4v*)(hsrc + jn);
    int4v hn1 = *(const int4v*)(hsrc + jn + 8);
    f32x4 nav0 = *(const f32x4*)(adjrow + jn);
    f32x4 nav1 = *(const f32x4*)(adjrow + jn + 4);
    f32x4 nsd0 = *(const f32x4*)(sdb + jn);
    f32x4 nsd1 = *(const f32x4*)(sdb + jn + 4);

    __syncthreads();                 // previous step's LDS reads done
    *(int4v*)hdst       = hc0;       // stage ht tile for this step
    *(int4v*)(hdst + 8) = hc1;
    __syncthreads();

    // weights: w_ij = adj_ij + exp(LR(si+sj) - m_i) * rl_i, in A-fragment layout
    float wv[8];
    wv[0] = av0[0] + __expf(lrelu(si + sd0[0]) - m_i) * rl_i;
    wv[1] = av0[1] + __expf(lrelu(si + sd0[1]) - m_i) * rl_i;
    wv[2] = av0[2] + __expf(lrelu(si + sd0[2]) - m_i) * rl_i;
    wv[3] = av0[3] + __expf(lrelu(si + sd0[3]) - m_i) * rl_i;
    wv[4] = av1[0] + __expf(lrelu(si + sd1[0]) - m_i) * rl_i;
    wv[5] = av1[1] + __expf(lrelu(si + sd1[1]) - m_i) * rl_i;
    wv[6] = av1[2] + __expf(lrelu(si + sd1[2]) - m_i) * rl_i;
    wv[7] = av1[3] + __expf(lrelu(si + sd1[3]) - m_i) * rl_i;
    bf16x8 af;
#pragma unroll
    for (int e = 0; e < 8; ++e) af[e] = (short)f2bf(wv[e]);

#pragma unroll
    for (int cg = 0; cg < 8; ++cg){
      const bf16x8 bf = *(const bf16x8*)(htl + (cg*16 + lr)*40 + hi*8);
      acc[cg] = __builtin_amdgcn_mfma_f32_16x16x32_bf16(af, bf, acc[cg], 0, 0, 0);
    }

    hc0 = hn0; hc1 = hn1;
    av0 = nav0; av1 = nav1;
    sd0 = nsd0; sd1 = nsd1;
  }

  // epilogue: C/D layout col=lane&15, row=(lane>>4)*4+q  [measured m89]
#pragma unroll
  for (int cg = 0; cg < 8; ++cg){
#pragma unroll
    for (int q = 0; q < 4; ++q){
      const int ri = i0 + wid*16 + hi*4 + q;
      const int co = cg*16 + lr;
      out[((long)b*2048 + ri)*128 + co] = lrelu(acc[cg][q]);
    }
  }
}

extern "C" void kernel_launch(void* const* d_in, const int* in_sizes, int n_in,
                              void* d_out, int out_size, void* d_ws, size_t ws_size,
                              hipStream_t stream){
  const float* x   = (const float*)d_in[0];
  const float* adj = (const float*)d_in[1];
  const float* W   = (const float*)d_in[2];
  const float* a   = (const float*)d_in[3];
  float* out = (float*)d_out;
  char* ws = (char*)d_ws;

  float*          h    = (float*)(ws);                        // 8 MB: [16384][128] f32
  unsigned short* ht   = (unsigned short*)(ws + 8388608);     // 4 MB: [8][128][2048] bf16
  float*          ssrc = (float*)(ws + 12582912);             // 64 KB
  float*          sdst = (float*)(ws + 12648448);             // 64 KB
  float*          M    = (float*)(ws + 12713984);             // 32 B
  float*          marr = (float*)(ws + 12714048);             // 64 KB
  float*          rlarr= (float*)(ws + 12779584);             // 64 KB

  k1_hgemm<<<512, 256, 0, stream>>>(x, W, h);
  k_tr    <<<512, 256, 0, stream>>>(h, ht);
  k2_s    <<<4096, 256, 0, stream>>>(h, a, ssrc, sdst);
  k2_max  <<<8,   256, 0, stream>>>(sdst, M);
  k2_ml   <<<4096, 256, 0, stream>>>(ssrc, sdst, M, marr, rlarr);
  k3_main <<<256, 256, 0, stream>>>(adj, ht, ssrc, sdst, marr, rlarr, out);
}